// Round 6
// baseline (138.839 us; speedup 1.0000x reference)
//
#include <hip/hip_runtime.h>
#include <stdint.h>

#define TABLE_BITS 21
#define TABLE_SIZE (1u << TABLE_BITS)      // 2,097,152 entries > max key 1,999,999
#define TABLE_MASK (TABLE_SIZE - 1u)
#define BLOCK 256
#define EPT 4
#define CHUNK (BLOCK * EPT)                // 1024 elements/block (flags/rank/out)
#define EPT2 16
#define CHUNK2 (BLOCK * EPT2)              // 4096 elements/block (scatter)
#define RANK_BIT 0x40000000
#define RANK_MASK 0x3FFFFFFF
#define NB 256                             // key-range buckets
#define BSHIFT (TABLE_BITS - 8)            // 8192 keys per bucket
#define KPB (1 << BSHIFT)
#define KLOW_MASK (KPB - 1)
#define INF_PAT 0x7f7f7f7f
#define BJ_INVALID 0xFFFFFFFFu
#define CAP 20480u                         // per-bucket region capacity (mean ~13.4K, +60 sigma)

// ---- block exclusive scan (NT threads) ----
template<int NT>
__device__ __forceinline__ int blk_excl_scan(int v, int tid, int* total) {
    constexpr int NW = NT / 64;
    int lane = tid & 63, w = tid >> 6;
    int inc = v;
    #pragma unroll
    for (int off = 1; off < 64; off <<= 1) {
        int u = __shfl_up(inc, off, 64);
        if (lane >= off) inc += u;
    }
    __shared__ int part[NW];
    if (lane == 63) part[w] = inc;
    __syncthreads();
    if (tid < NW) {
        int p = part[tid];
        #pragma unroll
        for (int off = 1; off < NW; off <<= 1) {
            int u = __shfl_up(p, off, 64);
            if (tid >= off) p += u;
        }
        part[tid] = p;
    }
    __syncthreads();
    int excl = ((w == 0) ? 0 : part[w - 1]) + inc - v;
    int tot = part[NW - 1];
    __syncthreads();
    if (total) *total = tot;
    return excl;
}

// ---------- C: single-pass scatter; bucket space allocated by global atomicAdd ----------
// Within-bucket pair order is nondeterministic across replays, but all consumers
// (min, flag, rank) are order-invariant, so d_out stays deterministic.
__global__ __launch_bounds__(BLOCK) void k_scatter(const int* __restrict__ x, int n,
                                                   unsigned* __restrict__ bucketCount,
                                                   unsigned* __restrict__ posArr,
                                                   unsigned short* __restrict__ klArr) {
    __shared__ unsigned cnt[NB];
    __shared__ unsigned lbase[NB + 1];
    __shared__ unsigned sbase[NB];
    __shared__ unsigned lpos[CHUNK2];              // 16 KB
    __shared__ unsigned short lkl[CHUNK2];         // 8 KB
    int tid = threadIdx.x;
    cnt[tid] = 0;
    __syncthreads();

    unsigned bjs[EPT2], kls[EPT2], los[EPT2];
    int e0 = blockIdx.x * CHUNK2;
    // pass 1: bucket ids + local offsets (LDS atomics)
    #pragma unroll
    for (int k = 0; k < EPT2 / 4; ++k) {
        int idx = e0 + k * (BLOCK * 4) + tid * 4;
        if (idx + 4 <= n) {
            int4 v = *reinterpret_cast<const int4*>(x + idx);
            unsigned kk[4] = {(unsigned)v.x & TABLE_MASK, (unsigned)v.y & TABLE_MASK,
                              (unsigned)v.z & TABLE_MASK, (unsigned)v.w & TABLE_MASK};
            #pragma unroll
            for (int j = 0; j < 4; ++j) {
                int e = k * 4 + j;
                bjs[e] = kk[j] >> BSHIFT;
                kls[e] = kk[j] & KLOW_MASK;
                los[e] = atomicAdd(&cnt[bjs[e]], 1u);
            }
        } else {
            #pragma unroll
            for (int j = 0; j < 4; ++j) {
                int e = k * 4 + j;
                int i = idx + j;
                if (i < n) {
                    unsigned kv = (unsigned)x[i] & TABLE_MASK;
                    bjs[e] = kv >> BSHIFT;
                    kls[e] = kv & KLOW_MASK;
                    los[e] = atomicAdd(&cnt[bjs[e]], 1u);
                } else {
                    bjs[e] = BJ_INVALID;
                }
            }
        }
    }
    __syncthreads();
    // local scan + global region allocation
    {
        int v = (int)cnt[tid];
        int tot;
        int ex = blk_excl_scan<256>(v, tid, &tot);
        lbase[tid] = (unsigned)ex;
        if (tid == 255) lbase[256] = (unsigned)(ex + v);
        unsigned gb = 0;
        if (v > 0) gb = atomicAdd(&bucketCount[tid], (unsigned)v);
        sbase[tid] = (unsigned)tid * CAP + gb;
    }
    __syncthreads();
    // pass 2: place into LDS ordered by bucket
    #pragma unroll
    for (int k = 0; k < EPT2 / 4; ++k) {
        #pragma unroll
        for (int j = 0; j < 4; ++j) {
            int e = k * 4 + j;
            if (bjs[e] != BJ_INVALID) {
                unsigned dst = lbase[bjs[e]] + los[e];
                lpos[dst] = (unsigned)(e0 + k * (BLOCK * 4) + tid * 4 + j);
                lkl[dst]  = (unsigned short)kls[e];
            }
        }
    }
    __syncthreads();
    // flush: wave per bucket, contiguous bursts
    int wv = tid >> 6, ln = tid & 63;
    for (int j = wv; j < NB; j += BLOCK / 64) {
        unsigned ls = lbase[j], len = lbase[j + 1] - ls;
        unsigned gs = sbase[j];
        unsigned gb = gs - (unsigned)j * CAP;
        unsigned avail = (gb < CAP) ? (CAP - gb) : 0;   // overflow guard (never in practice)
        if (len > avail) len = avail;
        for (unsigned i = ln; i < len; i += 64) {
            posArr[gs + i] = lpos[ls + i];
            klArr[gs + i]  = lkl[ls + i];
        }
    }
}

// ---------- D: per-bucket first-idx in LDS; coalesced table write + flag bytes ----------
__global__ __launch_bounds__(512) void k_bucket_min(const unsigned* __restrict__ posArr,
                                                    const unsigned short* __restrict__ klArr,
                                                    const unsigned* __restrict__ bucketCount,
                                                    int* __restrict__ table,
                                                    unsigned char* __restrict__ flag) {
    __shared__ int fi[KPB];                 // 32 KB
    int j = blockIdx.x, tid = threadIdx.x;
    for (int k = tid; k < KPB; k += 512) fi[k] = INF_PAT;
    __syncthreads();
    unsigned cnt = bucketCount[j];
    if (cnt > CAP) cnt = CAP;
    unsigned base = (unsigned)j * CAP;
    for (unsigned idx = tid; idx < cnt; idx += 512)
        atomicMin(&fi[klArr[base + idx]], (int)posArr[base + idx]);
    __syncthreads();
    int* dst = table + (size_t)j * KPB;
    for (int k = tid; k < KPB; k += 512) dst[k] = fi[k];
    // flag bytes: every position written exactly once (L2-hot re-read of pairs)
    for (unsigned idx = tid; idx < cnt; idx += 512) {
        unsigned pos = posArr[base + idx];
        flag[pos] = (unsigned char)(fi[klArr[base + idx]] == (int)pos);
    }
}

// ---------- E: sequential flag bytes -> bitmask + blockSums ----------
__global__ __launch_bounds__(BLOCK) void k_flags(const unsigned char* __restrict__ flag, int n,
                                                 int* __restrict__ blockSums,
                                                 unsigned long long* __restrict__ bitmask) {
    int tid = threadIdx.x;
    int lane = tid & 63, w = tid >> 6;
    int base = blockIdx.x * CHUNK + tid * EPT;
    int flags[EPT];
    if (base + EPT <= n) {
        uchar4 f = *reinterpret_cast<const uchar4*>(flag + base);
        flags[0] = f.x; flags[1] = f.y; flags[2] = f.z; flags[3] = f.w;
    } else {
        #pragma unroll
        for (int j = 0; j < EPT; ++j)
            flags[j] = (base + j < n) ? flag[base + j] : 0;
    }
    int cnt = 0;
    #pragma unroll
    for (int j = 0; j < EPT; ++j) {
        unsigned long long mj = __ballot(flags[j]);
        if (lane == 0) bitmask[((size_t)blockIdx.x * (BLOCK / 64) + w) * EPT + j] = mj;
        cnt += flags[j];
    }
    for (int off = 32; off > 0; off >>= 1)
        cnt += __shfl_down(cnt, off, 64);
    __shared__ int ws[BLOCK / 64];
    if (lane == 0) ws[w] = cnt;
    __syncthreads();
    if (tid == 0) {
        int s = 0;
        #pragma unroll
        for (int q = 0; q < BLOCK / 64; ++q) s += ws[q];
        blockSums[blockIdx.x] = s;
    }
}

// ---------- K3: single-block scan of blockSums ----------
__global__ __launch_bounds__(1024) void k_scan(int* __restrict__ sums, int B) {
    int tid = threadIdx.x;
    int carry = 0;
    for (int b0 = 0; b0 < B; b0 += 1024) {
        int b = b0 + tid;
        int v = (b < B) ? sums[b] : 0;
        int tot;
        int excl = blk_excl_scan<1024>(v, tid, &tot);
        if (b < B) sums[b] = carry + excl;
        carry += tot;
    }
}

// ---------- K4: assign ranks using the bitmask ----------
__global__ __launch_bounds__(BLOCK) void k_rank(const int* __restrict__ x, int n,
                                                int* __restrict__ table,
                                                const int* __restrict__ blockSums,
                                                const unsigned long long* __restrict__ bitmask) {
    int tid = threadIdx.x;
    int lane = tid & 63, w = tid >> 6;
    int base = blockIdx.x * CHUNK + tid * EPT;
    const unsigned long long* bm = bitmask + ((size_t)blockIdx.x * (BLOCK / 64) + w) * EPT;
    int flags[EPT];
    int cnt = 0;
    #pragma unroll
    for (int j = 0; j < EPT; ++j) {
        flags[j] = (int)((bm[j] >> lane) & 1ull);
        cnt += flags[j];
    }
    __shared__ int lds[BLOCK];
    lds[tid] = cnt;
    __syncthreads();
    for (int off = 1; off < BLOCK; off <<= 1) {
        int t = (tid >= off) ? lds[tid - off] : 0;
        __syncthreads();
        lds[tid] += t;
        __syncthreads();
    }
    int r = blockSums[blockIdx.x] + lds[tid] - cnt;
    if (cnt) {
        if (base + EPT <= n) {
            int4 v = *reinterpret_cast<const int4*>(x + base);
            if (flags[0]) table[(unsigned)v.x & TABLE_MASK] = (r++) | RANK_BIT;
            if (flags[1]) table[(unsigned)v.y & TABLE_MASK] = (r++) | RANK_BIT;
            if (flags[2]) table[(unsigned)v.z & TABLE_MASK] = (r++) | RANK_BIT;
            if (flags[3]) table[(unsigned)v.w & TABLE_MASK] = (r++) | RANK_BIT;
        } else {
            #pragma unroll
            for (int j = 0; j < EPT; ++j)
                if (flags[j]) table[(unsigned)x[base + j] & TABLE_MASK] = (r++) | RANK_BIT;
        }
    }
}

// ---------- K5: gather rank, apply max_tokens cutoff ----------
__global__ __launch_bounds__(BLOCK) void k_out(const int* __restrict__ x, int n,
                                               const int* __restrict__ table,
                                               const int* __restrict__ mtp,
                                               int* __restrict__ out) {
    int mt = mtp[0];
    int base = (blockIdx.x * BLOCK + threadIdx.x) * EPT;
    if (base + EPT <= n) {
        int4 v = *reinterpret_cast<const int4*>(x + base);
        int4 o;
        int r;
        r = table[(unsigned)v.x & TABLE_MASK] & RANK_MASK; o.x = (r < mt) ? r + 1 : 0;
        r = table[(unsigned)v.y & TABLE_MASK] & RANK_MASK; o.y = (r < mt) ? r + 1 : 0;
        r = table[(unsigned)v.z & TABLE_MASK] & RANK_MASK; o.z = (r < mt) ? r + 1 : 0;
        r = table[(unsigned)v.w & TABLE_MASK] & RANK_MASK; o.w = (r < mt) ? r + 1 : 0;
        *reinterpret_cast<int4*>(out + base) = o;
    } else {
        for (int i = base; i < n; ++i) {
            int r = table[(unsigned)x[i] & TABLE_MASK] & RANK_MASK;
            out[i] = (r < mt) ? r + 1 : 0;
        }
    }
}

// ---------- fallbacks (small ws): device-scope atomics + gather count ----------
__global__ __launch_bounds__(BLOCK) void k_first_idx(const int* __restrict__ x, int n,
                                                     int* __restrict__ table) {
    int base = (blockIdx.x * BLOCK + threadIdx.x) * EPT;
    for (int i = base; i < min(base + EPT, n); ++i)
        atomicMin(&table[(unsigned)x[i] & TABLE_MASK], i);
}
__global__ __launch_bounds__(BLOCK) void k_count(const int* __restrict__ x, int n,
                                                 const int* __restrict__ table,
                                                 int* __restrict__ blockSums,
                                                 unsigned long long* __restrict__ bitmask) {
    int tid = threadIdx.x;
    int lane = tid & 63, w = tid >> 6;
    int base = blockIdx.x * CHUNK + tid * EPT;
    int flags[EPT];
    #pragma unroll
    for (int j = 0; j < EPT; ++j) {
        flags[j] = 0;
        if (base + j < n)
            flags[j] = (table[(unsigned)x[base + j] & TABLE_MASK] == base + j);
    }
    int cnt = 0;
    #pragma unroll
    for (int j = 0; j < EPT; ++j) {
        unsigned long long mj = __ballot(flags[j]);
        if (lane == 0) bitmask[((size_t)blockIdx.x * (BLOCK / 64) + w) * EPT + j] = mj;
        cnt += flags[j];
    }
    for (int off = 32; off > 0; off >>= 1)
        cnt += __shfl_down(cnt, off, 64);
    __shared__ int ws[BLOCK / 64];
    if (lane == 0) ws[w] = cnt;
    __syncthreads();
    if (tid == 0) {
        int s = 0;
        #pragma unroll
        for (int q = 0; q < BLOCK / 64; ++q) s += ws[q];
        blockSums[blockIdx.x] = s;
    }
}

extern "C" void kernel_launch(void* const* d_in, const int* in_sizes, int n_in,
                              void* d_out, int out_size, void* d_ws, size_t ws_size,
                              hipStream_t stream) {
    const int* x   = (const int*)d_in[0];
    const int* mtp = (const int*)d_in[1];
    int n = in_sizes[0];
    int* out = (int*)d_out;

    int SB  = (n + CHUNK  - 1) / CHUNK;    // 1024-granularity blocks
    int SB2 = (n + CHUNK2 - 1) / CHUNK2;   // 4096-granularity blocks

    auto align16 = [](size_t v) { return (v + 15) & ~(size_t)15; };
    size_t off = 0;
    int* table = (int*)d_ws;                                    off = align16(off + (size_t)TABLE_SIZE * 4);
    unsigned* posArr = (unsigned*)((char*)d_ws + off);          off = align16(off + (size_t)NB * CAP * 4);
    unsigned short* klArr = (unsigned short*)((char*)d_ws + off); off = align16(off + (size_t)NB * CAP * 2);
    unsigned char* flag = (unsigned char*)((char*)d_ws + off);  off = align16(off + (size_t)n);
    unsigned* bucketCount = (unsigned*)((char*)d_ws + off);     off = align16(off + (size_t)NB * 4);
    int* blockSums = (int*)((char*)d_ws + off);                 off = align16(off + (size_t)SB * 4);
    unsigned long long* bitmask = (unsigned long long*)((char*)d_ws + off);
    off = align16(off + (size_t)SB * (BLOCK / 64) * EPT * 8);

    if (ws_size >= off) {
        hipMemsetAsync(bucketCount, 0, (size_t)NB * 4, stream);
        k_scatter   <<<SB2, BLOCK, 0, stream>>>(x, n, bucketCount, posArr, klArr);
        k_bucket_min<<<NB,  512,   0, stream>>>(posArr, klArr, bucketCount, table, flag);
        k_flags     <<<SB,  BLOCK, 0, stream>>>(flag, n, blockSums, bitmask);
    } else {
        // minimal-footprint fallback
        size_t foff = (size_t)TABLE_SIZE * 4;
        blockSums = (int*)((char*)d_ws + foff);   foff += (size_t)SB * 4;
        bitmask = (unsigned long long*)((char*)d_ws + ((foff + 15) & ~(size_t)15));
        hipMemsetAsync(table, 0x7F, (size_t)TABLE_SIZE * 4, stream);
        k_first_idx<<<SB, BLOCK, 0, stream>>>(x, n, table);
        k_count    <<<SB, BLOCK, 0, stream>>>(x, n, table, blockSums, bitmask);
    }
    k_scan <<<1, 1024, 0, stream>>>(blockSums, SB);
    k_rank <<<SB, BLOCK, 0, stream>>>(x, n, table, blockSums, bitmask);
    k_out  <<<SB, BLOCK, 0, stream>>>(x, n, table, mtp, out);
}